// Round 1
// baseline (211.543 us; speedup 1.0000x reference)
//
#include <hip/hip_runtime.h>

// Problem constants (from reference): B=16, T=2048, L=1024, D=512, K=5
#define ROWS   (16 * 2048)   // B*T
#define ROWLEN 1024          // L
#define DMODEL 512           // D

// Math: out[row,d] = (Aw[d]*s - w0[d]*x[L-2] - (w0+w1)[d]*x[L-1]
//                     - (w3+w4)[d]*x[0] - w4[d]*x[1]) / L + b[d]
// where s = sum over the row. Derived from mean-over-L of K=5 same-pad conv.

__global__ __launch_bounds__(256) void conv1d_token_encoder_kernel(
    const float* __restrict__ x,
    const float* __restrict__ w,
    const float* __restrict__ b,
    float* __restrict__ out)
{
    const int lane   = threadIdx.x & 63;
    const int wid    = blockIdx.x * (blockDim.x >> 6) + (threadIdx.x >> 6);
    const int nwaves = gridDim.x * (blockDim.x >> 6);
    const float invL = 1.0f / (float)ROWLEN;   // exact (power of two)

    // Hoist per-lane channel coefficients out of the row loop.
    // Lane owns channels d = 4*lane + 256*j + c  (j=0..1, c=0..3)
    // -> output stores are 2 coalesced float4 per lane.
    float cA[2][4], cm2[2][4], cm1[2][4], c0c[2][4], c1c[2][4], cb[2][4];
#pragma unroll
    for (int j = 0; j < 2; ++j) {
#pragma unroll
        for (int c = 0; c < 4; ++c) {
            const int d = 4 * lane + 256 * j + c;
            const float w0 = w[d * 5 + 0];
            const float w1 = w[d * 5 + 1];
            const float w2 = w[d * 5 + 2];
            const float w3 = w[d * 5 + 3];
            const float w4 = w[d * 5 + 4];
            cA[j][c]  = (w0 + w1 + w2 + w3 + w4) * invL;
            cm2[j][c] = w0 * invL;
            cm1[j][c] = (w0 + w1) * invL;
            c0c[j][c] = (w3 + w4) * invL;
            c1c[j][c] = w4 * invL;
            cb[j][c]  = b[d];
        }
    }

    for (int row = wid; row < ROWS; row += nwaves) {
        const float4* __restrict__ xr = (const float4*)(x + (size_t)row * ROWLEN);
        // 64 lanes x 4 float4 = 1024 floats, fully coalesced (16B/lane/instr)
        float4 v0 = xr[lane];
        float4 v1 = xr[lane + 64];
        float4 v2 = xr[lane + 128];
        float4 v3 = xr[lane + 192];

        float s = (v0.x + v0.y + v0.z + v0.w)
                + (v1.x + v1.y + v1.z + v1.w)
                + (v2.x + v2.y + v2.z + v2.w)
                + (v3.x + v3.y + v3.z + v3.w);
        // wave64 butterfly reduce -> every lane holds full row sum
#pragma unroll
        for (int m = 1; m < 64; m <<= 1) s += __shfl_xor(s, m, 64);

        // boundary elements, pulled from already-loaded fragments
        const float x0  = __shfl(v0.x, 0, 64);   // x[row, 0]
        const float x1  = __shfl(v0.y, 0, 64);   // x[row, 1]
        const float xm2 = __shfl(v3.z, 63, 64);  // x[row, L-2]
        const float xm1 = __shfl(v3.w, 63, 64);  // x[row, L-1]

        float4* __restrict__ orow = (float4*)(out + (size_t)row * DMODEL);
#pragma unroll
        for (int j = 0; j < 2; ++j) {
            float4 o;
            o.x = cA[j][0] * s - cm2[j][0] * xm2 - cm1[j][0] * xm1
                - c0c[j][0] * x0 - c1c[j][0] * x1 + cb[j][0];
            o.y = cA[j][1] * s - cm2[j][1] * xm2 - cm1[j][1] * xm1
                - c0c[j][1] * x0 - c1c[j][1] * x1 + cb[j][1];
            o.z = cA[j][2] * s - cm2[j][2] * xm2 - cm1[j][2] * xm1
                - c0c[j][2] * x0 - c1c[j][2] * x1 + cb[j][2];
            o.w = cA[j][3] * s - cm2[j][3] * xm2 - cm1[j][3] * xm1
                - c0c[j][3] * x0 - c1c[j][3] * x1 + cb[j][3];
            orow[lane + 64 * j] = o;  // coalesced float4 store
        }
    }
}

extern "C" void kernel_launch(void* const* d_in, const int* in_sizes, int n_in,
                              void* d_out, int out_size, void* d_ws, size_t ws_size,
                              hipStream_t stream) {
    const float* x = (const float*)d_in[0];  // [B,T,L] fp32
    const float* w = (const float*)d_in[1];  // [D,K]  fp32
    const float* b = (const float*)d_in[2];  // [D]    fp32
    float* out = (float*)d_out;              // [B,T,D] fp32

    // 2048 blocks x 4 waves = 8192 waves; 32768 rows -> 4 rows/wave
    conv1d_token_encoder_kernel<<<2048, 256, 0, stream>>>(x, w, b, out);
}